// Round 2
// baseline (1919.745 us; speedup 1.0000x reference)
//
#include <hip/hip_runtime.h>
#include <cstdint>

typedef __fp16 half2v __attribute__((ext_vector_type(2)));

#define S_ROW 3080   // dwords per LDS pair-row: blocks of 8 data + 4 pad dwords
#define W 2048
#define H 512

__device__ __forceinline__ half2v as_h2(uint32_t u) {
    union { uint32_t u; half2v h; } x; x.u = u; return x.h;
}
__device__ __forceinline__ uint32_t as_u32(half2v h) {
    union { uint32_t u; half2v h; } x; x.h = h; return x.u;
}

// ---------------- pack x[:,1:3,:,:] into half2 pairs (fully parallel) ----------------
__global__ __launch_bounds__(256) void pack_xi_kernel(const float* __restrict__ x,
                                                      uint32_t* __restrict__ xi) {
    int i  = blockIdx.x * 256 + threadIdx.x;    // 8*512*512 threads, 4 w each
    int wq = (i & 511) * 4;
    int t  = (i >> 9) & 511;
    int b  = i >> 18;
    const float* p1 = x + (((size_t)b*3 + 1)*H + t)*W + wq;
    const float* p2 = x + (((size_t)b*3 + 2)*H + t)*W + wq;
    float4 a = *(const float4*)p1;
    float4 c = *(const float4*)p2;
    uint4 o;
    o.x = as_u32(__builtin_amdgcn_cvt_pkrtz(a.x, c.x));
    o.y = as_u32(__builtin_amdgcn_cvt_pkrtz(a.y, c.y));
    o.z = as_u32(__builtin_amdgcn_cvt_pkrtz(a.z, c.z));
    o.w = as_u32(__builtin_amdgcn_cvt_pkrtz(a.w, c.w));
    *(uint4*)(xi + ((size_t)b*H + t)*W + wq) = o;
}

// ---------------- recurrence body (NOP = number of out channel-pairs for this wave group) ----------------
template<int NOP>
__device__ __forceinline__ void run_batch(
    int tid, int g,
    const uint32_t* __restrict__ xi, float* __restrict__ out,
    const float* __restrict__ wl, const float* __restrict__ bl,
    const float* __restrict__ wo, const float* __restrict__ bo,
    uint32_t* lds, int b)
{
    const int p = tid & 255;                 // position block within group

    // ---- weights resident in registers across all 512 steps ----
    half2v wp[NOP][2][6][3];                 // [out-pair][lo/hi ch][in-pair][tap]
    float  bias[NOP][2];
    #pragma unroll
    for (int op = 0; op < NOP; ++op) {
        int P = 2*op + g;                    // g0 -> pairs 0,2,4 ; g1 -> pairs 1,3
        #pragma unroll
        for (int s = 0; s < 2; ++s) {
            int c = 2*P + s;
            bias[op][s] = bl[c];
            #pragma unroll
            for (int cp = 0; cp < 6; ++cp)
                #pragma unroll
                for (int k = 0; k < 3; ++k) {
                    half2v wv;
                    wv.x = (__fp16)wl[(c*12 + 2*cp    )*3 + k];
                    wv.y = (__fp16)wl[(c*12 + 2*cp + 1)*3 + k];
                    wp[op][s][cp][k] = wv;
                }
        }
    }
    half2v wop[5];
    #pragma unroll
    for (int cp = 0; cp < 5; ++cp) {
        half2v wv; wv.x = (__fp16)wo[2*cp]; wv.y = (__fp16)wo[2*cp+1];
        wop[cp] = wv;
    }
    const float bov = bo[0];

    float*          outb = out + (size_t)b * H * W;
    const uint32_t* xib  = xi  + (size_t)b * H * W;

    // ---- phase C for t = 0 (row0 already in LDS) ----
    {
        const int idxc = 4*tid + 4*(tid >> 1);
        float o0=bov,o1=bov,o2=bov,o3=bov;
        #pragma unroll
        for (int cp = 0; cp < 5; ++cp) {
            uint4 q = *(const uint4*)&lds[cp*S_ROW + idxc];
            o0 = __builtin_amdgcn_fdot2(wop[cp], as_h2(q.x), o0, false);
            o1 = __builtin_amdgcn_fdot2(wop[cp], as_h2(q.y), o1, false);
            o2 = __builtin_amdgcn_fdot2(wop[cp], as_h2(q.z), o2, false);
            o3 = __builtin_amdgcn_fdot2(wop[cp], as_h2(q.w), o3, false);
        }
        *(float4*)(outb + 4*tid) = make_float4(o0,o1,o2,o3);
    }

    #pragma unroll 1
    for (int t = 1; t < H; ++t) {
        // ---------- phase A: compute new row into registers ----------
        const uint32_t* xr = xib + (size_t)t*W + 8*p;   // xi pairs, w = 8p..8p+9
        uint4 xa = *(const uint4*)xr;
        uint4 xb = *(const uint4*)(xr + 4);
        uint2 xc;
        if (p < 255) xc = *(const uint2*)(xr + 8);
        else { xc.x = 0u; xc.y = 0u; }                  // avoid OOB read; results discarded
        uint32_t xd[10] = {xa.x,xa.y,xa.z,xa.w, xb.x,xb.y,xb.z,xb.w, xc.x,xc.y};

        float acc[NOP][2][8];
        #pragma unroll
        for (int op = 0; op < NOP; ++op)
            #pragma unroll
            for (int s = 0; s < 2; ++s)
                #pragma unroll
                for (int i = 0; i < 8; ++i)
                    acc[op][s][i] = bias[op][s];

        #pragma unroll
        for (int cp = 0; cp < 5; ++cp) {
            const uint32_t* row = &lds[cp*S_ROW + 12*p];
            uint4 fa = *(const uint4*)row;              // w 8p..8p+3
            uint4 fb = *(const uint4*)(row + 4);        // w 8p+4..8p+7
            uint2 fc = *(const uint2*)(row + 12);       // w 8p+8..8p+9 (next block)
            uint32_t fd[10] = {fa.x,fa.y,fa.z,fa.w, fb.x,fb.y,fb.z,fb.w, fc.x,fc.y};
            #pragma unroll
            for (int op = 0; op < NOP; ++op)
                #pragma unroll
                for (int s = 0; s < 2; ++s)
                    #pragma unroll
                    for (int k = 0; k < 3; ++k) {
                        half2v wv = wp[op][s][cp][k];
                        #pragma unroll
                        for (int i = 0; i < 8; ++i)
                            acc[op][s][i] = __builtin_amdgcn_fdot2(wv, as_h2(fd[i+k]), acc[op][s][i], false);
                    }
        }
        #pragma unroll
        for (int op = 0; op < NOP; ++op)                // xi contribution (in-pair 5)
            #pragma unroll
            for (int s = 0; s < 2; ++s)
                #pragma unroll
                for (int k = 0; k < 3; ++k) {
                    half2v wv = wp[op][s][5][k];
                    #pragma unroll
                    for (int i = 0; i < 8; ++i)
                        acc[op][s][i] = __builtin_amdgcn_fdot2(wv, as_h2(xd[i+k]), acc[op][s][i], false);
                }

        __syncthreads();   // all reads of prev row done

        // ---------- phase B: relu, pack, write new row ----------
        #pragma unroll
        for (int op = 0; op < NOP; ++op) {
            int P = 2*op + g;
            uint32_t* row = &lds[P*S_ROW];
            uint32_t v[8];
            #pragma unroll
            for (int i = 0; i < 8; ++i) {
                float lo = fmaxf(acc[op][0][i], 0.f);
                float hi = fmaxf(acc[op][1][i], 0.f);
                v[i] = as_u32(__builtin_amdgcn_cvt_pkrtz(lo, hi));
            }
            // w = 8p+1 .. 8p+8  ->  idx 12p+1..12p+7, 12p+12
            if (p < 255) {
                row[12*p + 1] = v[0];
                uint2 v12; v12.x = v[1]; v12.y = v[2];
                *(uint2*)(row + 12*p + 2) = v12;
                uint4 v36; v36.x=v[3]; v36.y=v[4]; v36.z=v[5]; v36.w=v[6];
                *(uint4*)(row + 12*p + 4) = v36;
                row[12*p + 12] = v[7];
            } else {                                     // only w 2041..2046 valid
                row[12*p + 1] = v[0];
                row[12*p + 2] = v[1];
                row[12*p + 3] = v[2];
                row[12*p + 4] = v[3];
                row[12*p + 5] = v[4];
                row[12*p + 6] = v[5];
            }
        }

        __syncthreads();   // new row visible

        // ---------- phase C: fused 1x1 conv -> out row t ----------
        {
            const int idxc = 4*tid + 4*(tid >> 1);
            float o0=bov,o1=bov,o2=bov,o3=bov;
            #pragma unroll
            for (int cp = 0; cp < 5; ++cp) {
                uint4 q = *(const uint4*)&lds[cp*S_ROW + idxc];
                o0 = __builtin_amdgcn_fdot2(wop[cp], as_h2(q.x), o0, false);
                o1 = __builtin_amdgcn_fdot2(wop[cp], as_h2(q.y), o1, false);
                o2 = __builtin_amdgcn_fdot2(wop[cp], as_h2(q.z), o2, false);
                o3 = __builtin_amdgcn_fdot2(wop[cp], as_h2(q.w), o3, false);
            }
            *(float4*)(outb + (size_t)t*W + 4*tid) = make_float4(o0,o1,o2,o3);
        }
    }
}

// ---------------- one workgroup per batch ----------------
__global__ __launch_bounds__(512, 2) void recurrent_kernel(
    const float* __restrict__ x,
    const float* __restrict__ w1, const float* __restrict__ b1,
    const float* __restrict__ w2, const float* __restrict__ b2,
    const float* __restrict__ wl, const float* __restrict__ bl,
    const float* __restrict__ wo, const float* __restrict__ bo,
    const uint32_t* __restrict__ xi, float* __restrict__ out)
{
    __shared__ uint32_t lds[5 * S_ROW];    // 61.6 KB, half2 channel pairs, block-swizzled
    const int tid = threadIdx.x;
    const int b   = blockIdx.x;

    for (int i = tid; i < 5*S_ROW; i += 512) lds[i] = 0;   // zeros: borders + guard region
    __syncthreads();

    // ---- init: row0 = relu(conv2('same', relu(conv1('valid', first_in)))) padded ----
    {
        const float* f0 = x + (((size_t)b*3 + 0)*H + (H-1))*W;  // x[b,0,-1,:]
        const float* f1 = x + (((size_t)b*3 + 1)*H + 0)*W;      // x[b,1,0,:]
        const float* f2 = x + (((size_t)b*3 + 2)*H + 0)*W;      // x[b,2,0,:]
        float fi[3][8];
        const int v0 = 4*tid - 1;
        #pragma unroll
        for (int l = 0; l < 8; ++l) {
            int v = v0 + l;
            bool ok = (v >= 0) && (v < W);
            fi[0][l] = ok ? f0[v] : 0.f;
            fi[1][l] = ok ? f1[v] : 0.f;
            fi[2][l] = ok ? f2[v] : 0.f;
        }
        float h1v[5][6];
        #pragma unroll
        for (int c = 0; c < 5; ++c)
            #pragma unroll
            for (int i6 = 0; i6 < 6; ++i6) {
                int u = v0 + i6;               // h1 position (valid 0..2045, else 'same' pad 0)
                float a = b1[c];
                #pragma unroll
                for (int j = 0; j < 3; ++j)
                    #pragma unroll
                    for (int k = 0; k < 3; ++k)
                        a += w1[(c*3 + j)*3 + k] * fi[j][i6 + k];
                h1v[c][i6] = (u >= 0 && u <= W-3) ? fmaxf(a, 0.f) : 0.f;
            }
        #pragma unroll
        for (int m = 0; m < 4; ++m) {
            int w = 4*tid + 1 + m;             // row0 interior w = 1..2046
            if (w <= W - 2) {
                float h2c[10];
                #pragma unroll
                for (int c2 = 0; c2 < 10; ++c2) {
                    float a = b2[c2];
                    #pragma unroll
                    for (int c = 0; c < 5; ++c)
                        #pragma unroll
                        for (int k = 0; k < 3; ++k)
                            a += w2[(c2*5 + c)*3 + k] * h1v[c][m + k];
                    h2c[c2] = fmaxf(a, 0.f);
                }
                int idx = w + 4*(w >> 3);
                #pragma unroll
                for (int cp = 0; cp < 5; ++cp)
                    lds[cp*S_ROW + idx] = as_u32(__builtin_amdgcn_cvt_pkrtz(h2c[2*cp], h2c[2*cp+1]));
            }
        }
    }
    __syncthreads();

    const int g = tid >> 8;   // waves 0-3 -> group 0 (6 ch), waves 4-7 -> group 1 (4 ch)
    if (g == 0) run_batch<3>(tid, 0, xi, out, wl, bl, wo, bo, lds, b);
    else        run_batch<2>(tid, 1, xi, out, wl, bl, wo, bo, lds, b);
}

extern "C" void kernel_launch(void* const* d_in, const int* in_sizes, int n_in,
                              void* d_out, int out_size, void* d_ws, size_t ws_size,
                              hipStream_t stream)
{
    const float* x  = (const float*)d_in[0];
    const float* w1 = (const float*)d_in[1];
    const float* b1 = (const float*)d_in[2];
    const float* w2 = (const float*)d_in[3];
    const float* b2 = (const float*)d_in[4];
    const float* wl = (const float*)d_in[5];
    const float* bl = (const float*)d_in[6];
    const float* wo = (const float*)d_in[7];
    const float* bo = (const float*)d_in[8];
    float* out   = (float*)d_out;
    uint32_t* xi = (uint32_t*)d_ws;     // 8*512*2048 half2 = 32 MB scratch

    pack_xi_kernel<<<8192, 256, 0, stream>>>(x, xi);
    recurrent_kernel<<<8, 512, 0, stream>>>(x, w1, b1, w2, b2, wl, bl, wo, bo, xi, out);
}